// Round 10
// baseline (226.085 us; speedup 1.0000x reference)
//
#include <hip/hip_runtime.h>
#include <cfloat>
#include <climits>

// Retriever: cosine-sim top-5 over 100k knowledge vectors + gather.
// v10: barrier-free sims. Each WAVE independently owns tiles of 16 ke rows x
// all 64 queries: B-frags stream f32->reg (ring-4, continuous issue, imm
// offsets), in-reg bf16 convert via v_perm, norms from in-loop sumsq + 2
// shfl, 4 MFMA/step. Intra-wave top-8 tail via private LDS slice. Block
// merge only at kernel end. Then merge -> top-16 -> exact f32 rescore.

#define BQ 64
#define DD 768
#define NK 100000
#define LK 32
#define K_TOP 5
#define TROWS 16                    // ke rows per tile
#define NTIL (NK / TROWS)           // 6250 (exact)
#define NBLK 768                    // sims blocks (4 waves each)
#define NWAV (NBLK * 4)             // 3072 waves, grid-stride over tiles
#define T_CAND 16                   // rescore candidate count

typedef __attribute__((ext_vector_type(8))) short short8;
typedef __attribute__((ext_vector_type(4))) float f32x4;

static __device__ __forceinline__ ushort bf16_rtn(float x) {
    uint u = __float_as_uint(x);
    return (ushort)((u + 0x7FFFu + ((u >> 16) & 1u)) >> 16);
}

#define INS8(v, n, va, ia)                                                  \
    _Pragma("unroll")                                                       \
    for (int m_ = 0; m_ < 8; ++m_) {                                        \
        if ((v) > va[m_]) {                                                 \
            float tv_ = va[m_]; va[m_] = (v); (v) = tv_;                    \
            int ti_ = ia[m_]; ia[m_] = (n); (n) = ti_;                      \
        }                                                                   \
    }

// ---------- phase 0: query -> normalized bf16 (row-major) + exact f32 norm ----------
__global__ __launch_bounds__(256) void prep_kernel(const float* __restrict__ q,
                                                   ushort* __restrict__ qbf,
                                                   float* __restrict__ qn) {
    const int b = blockIdx.x, t = threadIdx.x;
    __shared__ float red[4];
    float v[3];
    float s = 0.f;
#pragma unroll
    for (int i = 0; i < 3; ++i) {
        v[i] = q[b * DD + t + i * 256];
        s = fmaf(v[i], v[i], s);
    }
    for (int off = 32; off > 0; off >>= 1) s += __shfl_down(s, off, 64);
    if ((t & 63) == 0) red[t >> 6] = s;
    __syncthreads();
    const float tot = red[0] + red[1] + red[2] + red[3];
    const float rq = rsqrtf(tot);
#pragma unroll
    for (int i = 0; i < 3; ++i)
        qbf[b * DD + t + i * 256] = bf16_rtn(v[i] * rq);
    if (t == 0) qn[b] = sqrtf(tot);
}

// ---------- phase 1: barrier-free wave-independent sims + top-8 ----------
__global__ __launch_bounds__(256) void sims_kernel(const ushort* __restrict__ qbf,
                                                   const float* __restrict__ ke,
                                                   float2* __restrict__ pv) {
    __shared__ float  S[4][BQ][17];     // per-wave private S slice (17: pad)
    __shared__ float2 mg[256 * 8];      // end-of-kernel block merge

    const int t = threadIdx.x;
    const int w = t >> 6, l = t & 63;
    const int lg = l >> 4, li = l & 15;

    float v8[8]; int i8[8];
#pragma unroll
    for (int m = 0; m < 8; ++m) { v8[m] = -FLT_MAX; i8[m] = INT_MAX; }

    // A base: lane li = q-row within group, lg = k-slice; L2-hot (96KB)
    const ushort* abase = qbf + (size_t)li * DD + lg * 8;

    const int gw = blockIdx.x * 4 + w;
    for (int tile = gw; tile < NTIL; tile += NWAV) {
        const int n0 = tile * TROWS;
        const float* bbase = ke + (size_t)(n0 + li) * DD + lg * 8;

        f32x4  br[4][2];                // B ring-4 (32B/step/lane)
        short8 ar[2][4];                // A ring-2 x 4 q-groups

        // prologue: 4 B-steps + 2 A-steps in flight
#pragma unroll
        for (int p = 0; p < 4; ++p) {
            br[p][0] = *(const f32x4*)(bbase + p * 32);
            br[p][1] = *(const f32x4*)(bbase + p * 32 + 4);
        }
#pragma unroll
        for (int s = 0; s < 2; ++s)
#pragma unroll
            for (int g = 0; g < 4; ++g)
                ar[s][g] = *(const short8*)(abase + (size_t)g * 16 * DD + s * 32);

        f32x4 acc[4];
#pragma unroll
        for (int g = 0; g < 4; ++g) acc[g] = (f32x4){0.f, 0.f, 0.f, 0.f};
        float bsq = 0.f;

#pragma unroll
        for (int kt = 0; kt < 24; ++kt) {
            const int cb = kt & 3, ca = kt & 1;
            // convert current B 8xf32 -> bf16x8 (trunc via v_perm) + sumsq
            union { short8 s8; uint u[4]; } pk;
#pragma unroll
            for (int p = 0; p < 4; ++p) {
                float f0 = br[cb][p >> 1][(p & 1) * 2 + 0];
                float f1 = br[cb][p >> 1][(p & 1) * 2 + 1];
                bsq = fmaf(f0, f0, bsq);
                bsq = fmaf(f1, f1, bsq);
                pk.u[p] = __builtin_amdgcn_perm(__float_as_uint(f1),
                                                __float_as_uint(f0), 0x07060302u);
            }
#pragma unroll
            for (int g = 0; g < 4; ++g)
                acc[g] = __builtin_amdgcn_mfma_f32_16x16x32_bf16(
                    ar[ca][g], pk.s8, acc[g], 0, 0, 0);
            // continuous issue: refill rings (WAR-safe: reads precede loads)
            if (kt < 20) {
                br[cb][0] = *(const f32x4*)(bbase + (kt + 4) * 32);
                br[cb][1] = *(const f32x4*)(bbase + (kt + 4) * 32 + 4);
            }
            if (kt < 22) {
#pragma unroll
                for (int g = 0; g < 4; ++g)
                    ar[ca][g] = *(const short8*)(abase + (size_t)g * 16 * DD
                                                 + (kt + 2) * 32);
            }
        }

        // row norm: lane li's bsq covers its lg k-subset; sum across lg groups
        bsq += __shfl_xor(bsq, 16, 64);
        bsq += __shfl_xor(bsq, 32, 64);
        const float rk = rsqrtf(bsq);

        // S slice (C layout: col(n)=li, row(q in group)=lg*4+r), intra-wave
#pragma unroll
        for (int g = 0; g < 4; ++g)
#pragma unroll
            for (int r = 0; r < 4; ++r)
                S[w][g * 16 + lg * 4 + r][li] = acc[g][r] * rk;
        // same-wave LDS write->read: in-order, compiler inserts lgkmcnt
#pragma unroll
        for (int j = 0; j < TROWS; ++j) {
            float v = S[w][l][j];
            int n = n0 + j;
            INS8(v, n, v8, i8);
        }
    }

    // ---- end-of-kernel block merge (only barriers in the kernel) ----
    __syncthreads();
#pragma unroll
    for (int m = 0; m < 8; ++m) mg[t * 8 + m] = make_float2(v8[m], __int_as_float(i8[m]));
    __syncthreads();
    if (t < BQ) {
        float vf[8]; int nf[8];
#pragma unroll
        for (int m = 0; m < 8; ++m) { vf[m] = -FLT_MAX; nf[m] = INT_MAX; }
        for (int s = 0; s < 4; ++s) {
            const float2* rowp = &mg[(t + s * 64) * 8];
#pragma unroll
            for (int m = 0; m < 8; ++m) {
                float v = rowp[m].x; int n = __float_as_int(rowp[m].y);
                INS8(v, n, vf, nf);
            }
        }
        float2* dst = pv + ((size_t)t * NBLK + blockIdx.x) * 8;
#pragma unroll
        for (int m = 0; m < 8; ++m) dst[m] = make_float2(vf[m], __int_as_float(nf[m]));
    }
}

// ---------- phase 2: merge 768x8 -> top-16 -> exact f32 rescore -> top-5 -> gather ----------
__global__ __launch_bounds__(256) void merge_rescore_kernel(
    const float2* __restrict__ pv,
    const float* __restrict__ q, const float* __restrict__ ke,
    const int* __restrict__ kf, const float* __restrict__ qn,
    float* __restrict__ out) {
    const int qi = blockIdx.x, t = threadIdx.x;
    __shared__ float sv[256][8];
    __shared__ int   si[256][8];
    __shared__ int   ci[T_CAND];
    __shared__ float cs_[T_CAND];
    __shared__ int   fi[K_TOP];

    float v8[8]; int i8[8];
#pragma unroll
    for (int m = 0; m < 8; ++m) { v8[m] = -FLT_MAX; i8[m] = INT_MAX; }

    // coalesced scan of this query's partials [NBLK*8 = 6144]
    const float2* src = pv + (size_t)qi * NBLK * 8;
    for (int c = t; c < NBLK * 8; c += 256) {
        float2 e = src[c];
        float v = e.x; int n = __float_as_int(e.y);
        INS8(v, n, v8, i8);
    }
#pragma unroll
    for (int m = 0; m < 8; ++m) { sv[t][m] = v8[m]; si[t][m] = i8[m]; }
    __syncthreads();

    // tree merge 256 -> 64 -> 16 -> 4 rows (top-8 each; global rank<=8 survives)
    for (int active = 64; active >= 4; active >>= 2) {
        if (t < active) {
#pragma unroll
            for (int m = 0; m < 8; ++m) { v8[m] = -FLT_MAX; i8[m] = INT_MAX; }
            for (int s = 0; s < 4; ++s) {
                int row = t * 4 + s;
#pragma unroll
                for (int m = 0; m < 8; ++m) {
                    float v = sv[row][m]; int n = si[row][m];
                    INS8(v, n, v8, i8);
                }
            }
        }
        __syncthreads();
        if (t < active) {
#pragma unroll
            for (int m = 0; m < 8; ++m) { sv[t][m] = v8[m]; si[t][m] = i8[m]; }
        }
        __syncthreads();
    }

    // thread 0: 4 rows x 8 -> top-16
    if (t == 0) {
        float v16[T_CAND]; int i16[T_CAND];
#pragma unroll
        for (int m = 0; m < T_CAND; ++m) { v16[m] = -FLT_MAX; i16[m] = INT_MAX; }
        for (int row = 0; row < 4; ++row) {
#pragma unroll
            for (int m = 0; m < 8; ++m) {
                float v = sv[row][m]; int n = si[row][m];
#pragma unroll
                for (int p = 0; p < T_CAND; ++p) {
                    if (v > v16[p]) {
                        float tv = v16[p]; v16[p] = v; v = tv;
                        int ti = i16[p]; i16[p] = n; n = ti;
                    }
                }
            }
        }
#pragma unroll
        for (int m = 0; m < T_CAND; ++m) ci[m] = i16[m];
    }
    __syncthreads();

    // exact f32 rescore; wave w -> candidates w*4..w*4+3
    {
        const int w = t >> 6, lane = t & 63;
        for (int cc = 0; cc < 4; ++cc) {
            int c = w * 4 + cc;
            int row = ci[c];
            const float* kp = ke + (size_t)row * DD + lane * 12;
            const float* qp = q + qi * DD + lane * 12;
            float d = 0.f, ks = 0.f;
#pragma unroll
            for (int i = 0; i < 12; ++i) {
                float kv = kp[i];
                d = fmaf(qp[i], kv, d);
                ks = fmaf(kv, kv, ks);
            }
#pragma unroll
            for (int off = 32; off > 0; off >>= 1) {
                d += __shfl_xor(d, off, 64);
                ks += __shfl_xor(ks, off, 64);
            }
            if (lane == 0)
                cs_[c] = d / fmaxf(qn[qi] * sqrtf(ks), 1e-8f);
        }
    }
    __syncthreads();

    // final top-5 of 16 (tie -> lower index)
    if (t == 0) {
        float v5[K_TOP]; int i5[K_TOP];
#pragma unroll
        for (int m = 0; m < K_TOP; ++m) { v5[m] = -FLT_MAX; i5[m] = INT_MAX; }
        for (int c = 0; c < T_CAND; ++c) {
            float v = cs_[c]; int n = ci[c];
#pragma unroll
            for (int m = 0; m < K_TOP; ++m) {
                bool take = (v > v5[m]) || (v == v5[m] && n < i5[m]);
                if (take) {
                    float tv = v5[m]; v5[m] = v; v = tv;
                    int ti = i5[m]; i5[m] = n; n = ti;
                }
            }
        }
#pragma unroll
        for (int m = 0; m < K_TOP; ++m) fi[m] = i5[m];
    }
    __syncthreads();

    // gather knowledge_full rows (ints < 30000 exact in f32)
    for (int pos = t; pos < K_TOP * LK; pos += 256) {
        int m = pos >> 5, lgi = pos & 31;
        out[(qi * K_TOP + m) * LK + lgi] = (float)kf[(size_t)fi[m] * LK + lgi];
    }
    // gather embed rows
    const int EO = BQ * K_TOP * LK;  // 10240
    for (int m = 0; m < K_TOP; ++m) {
        const float4* srcp = (const float4*)(ke + (size_t)fi[m] * DD);
        float4* dstp = (float4*)(out + EO + (size_t)(qi * K_TOP + m) * DD);
        for (int pos = t; pos < DD / 4; pos += 256) dstp[pos] = srcp[pos];
    }
}

extern "C" void kernel_launch(void* const* d_in, const int* in_sizes, int n_in,
                              void* d_out, int out_size, void* d_ws, size_t ws_size,
                              hipStream_t stream) {
    const float* query = (const float*)d_in[0];
    const float* ke    = (const float*)d_in[1];
    const int*   kf    = (const int*)d_in[2];
    float* out = (float*)d_out;

    // ws layout: pv [64][768][8] float2 (3.1 MB) | qbf [64*768] ushort | qn[64]
    float2* pv  = (float2*)d_ws;
    ushort* qbf = (ushort*)((char*)d_ws + (size_t)BQ * NBLK * 8 * sizeof(float2));
    float*  qn  = (float*)((char*)qbf + (size_t)BQ * DD * sizeof(ushort));

    prep_kernel<<<BQ, 256, 0, stream>>>(query, qbf, qn);
    sims_kernel<<<NBLK, 256, 0, stream>>>(qbf, ke, pv);
    merge_rescore_kernel<<<BQ, 256, 0, stream>>>(pv, query, ke, kf, qn, out);
}

// Round 11
// 163.792 us; speedup vs baseline: 1.3803x; 1.3803x over previous
//
#include <hip/hip_runtime.h>
#include <cfloat>
#include <climits>

// Retriever: cosine-sim top-5 over 100k knowledge vectors + gather.
// v11 = v9 (persistent 512 blocks, issue-early/consume-late staging,
// fragment-major Q, quarter-parallel top-8 tail) with the per-row norm
// chain removed: row norms via Gram-MFMA diag (ncc = mfma(B,B,ncc)),
// convert = pure v_perm truncation. Then merge -> top-16 -> exact f32
// rescore -> top-5 -> gather.

#define BQ 64
#define DD 768
#define NK 100000
#define LK 32
#define K_TOP 5
#define TROWS 16                    // ke rows per tile
#define NTIL (NK / TROWS)           // 6250 (exact)
#define NBLKS 512                   // persistent sims blocks (all resident)
#define T_CAND 16                   // rescore candidate count

typedef __attribute__((ext_vector_type(8))) short short8;
typedef __attribute__((ext_vector_type(4))) float f32x4;

static __device__ __forceinline__ ushort bf16_rtn(float x) {
    uint u = __float_as_uint(x);
    return (ushort)((u + 0x7FFFu + ((u >> 16) & 1u)) >> 16);
}

#define INS8(v, n, va, ia)                                                  \
    _Pragma("unroll")                                                       \
    for (int m_ = 0; m_ < 8; ++m_) {                                        \
        if ((v) > va[m_]) {                                                 \
            float tv_ = va[m_]; va[m_] = (v); (v) = tv_;                    \
            int ti_ = ia[m_]; ia[m_] = (n); (n) = ti_;                      \
        }                                                                   \
    }

// ---------- phase 0: query -> normalized bf16 in FRAGMENT-MAJOR layout ----------
// qf[((kt*4 + (b>>4))*64 + lg*16 + (b&15))*8 + j] = bf16(q[b][kt*32+lg*8+j] * rq)
__global__ __launch_bounds__(256) void prep_kernel(const float* __restrict__ q,
                                                   ushort* __restrict__ qf,
                                                   float* __restrict__ qn) {
    const int b = blockIdx.x, t = threadIdx.x;
    __shared__ float red[4];
    float v[3];
    float s = 0.f;
#pragma unroll
    for (int i = 0; i < 3; ++i) {
        v[i] = q[b * DD + t + i * 256];
        s = fmaf(v[i], v[i], s);
    }
    for (int off = 32; off > 0; off >>= 1) s += __shfl_down(s, off, 64);
    if ((t & 63) == 0) red[t >> 6] = s;
    __syncthreads();
    const float tot = red[0] + red[1] + red[2] + red[3];
    const float rq = rsqrtf(tot);
    const int qb = b >> 4, bi = b & 15;
#pragma unroll
    for (int i = 0; i < 3; ++i) {
        const int k = t + i * 256;
        const int kt = k >> 5, lg = (k >> 3) & 3, j = k & 7;
        qf[((size_t)(kt * 4 + qb) * 64 + lg * 16 + bi) * 8 + j] = bf16_rtn(v[i] * rq);
    }
    if (t == 0) qn[b] = sqrtf(tot);
}

// ---------- phase 1: persistent sims + Gram norms + fused top-8 ----------
__global__ __launch_bounds__(256) void sims_kernel(const ushort* __restrict__ qf,
                                                   const float* __restrict__ ke,
                                                   float2* __restrict__ pv) {
    __shared__ ushort Bb[2][TROWS * DD];   // 2 x 24576 B, raw trunc bf16, swizzled
    __shared__ float  S[BQ][17];           // sims tile (bank-spread)

    const int t = threadIdx.x;
    const int w = t >> 6, l = t & 63;
    const int lg = l >> 4, li = l & 15;
    const int qd = t & 63, jq = t >> 6;    // tail: query + column-quarter

    float v8[8]; int i8[8];
#pragma unroll
    for (int m = 0; m < 8; ++m) { v8[m] = -FLT_MAX; i8[m] = INT_MAX; }

    f32x4 sr[4][3];                        // reg-staged 4 rows x 48B/lane
    int tile = blockIdx.x;

    // prologue: issue stage loads for first tile (coalesced 1KB/instr)
    {
        const float* g = ke + (size_t)(tile * TROWS + w * 4) * DD + l * 4;
#pragma unroll
        for (int i = 0; i < 4; ++i)
#pragma unroll
            for (int c = 0; c < 3; ++c)
                sr[i][c] = *(const f32x4*)(g + i * DD + c * 256);
    }

    int cur = 0;
    while (true) {
        const int nxt = tile + NBLKS;

        // ---- convert own 4 rows -> raw trunc bf16 -> Bb[cur] (swizzled) ----
        // No norms here: 6 v_perm + 3 stores per row, zero serial chains.
        char* bb = (char*)(&Bb[cur][0]);
#pragma unroll
        for (int i = 0; i < 4; ++i) {
            const int row = w * 4 + i;
            const int base = row * 1536 + l * 8;
            const int sw = (row & 7) << 4;
#pragma unroll
            for (int c = 0; c < 3; ++c) {
                uint2 u;
                u.x = __builtin_amdgcn_perm(__float_as_uint(sr[i][c][1]),
                                            __float_as_uint(sr[i][c][0]),
                                            0x07060302u);
                u.y = __builtin_amdgcn_perm(__float_as_uint(sr[i][c][3]),
                                            __float_as_uint(sr[i][c][2]),
                                            0x07060302u);
                *(uint2*)(bb + ((base + c * 512) ^ sw)) = u;
            }
        }
        // ---- issue next tile's stage loads (fly under the K-loop) ----
        if (nxt < NTIL) {
            const float* g = ke + (size_t)(nxt * TROWS + w * 4) * DD + l * 4;
#pragma unroll
            for (int i = 0; i < 4; ++i)
#pragma unroll
                for (int c = 0; c < 3; ++c)
                    sr[i][c] = *(const f32x4*)(g + i * DD + c * 256);
        }
        asm volatile("s_waitcnt lgkmcnt(0)" ::: "memory");
        __builtin_amdgcn_sched_barrier(0);
        __builtin_amdgcn_s_barrier();      // raw: does NOT drain vmcnt
        __builtin_amdgcn_sched_barrier(0);

        // ---- K-loop: 24 x (A-load + ds_read + 2 MFMA: sims + Gram) ----
        const ushort* aq = qf + (size_t)w * 512 + l * 8;   // +kt*2048/step
        const int boff = li * 1536 + lg * 16;
        const int bsw = (li & 7) << 4;
        f32x4 acc = (f32x4){0.f, 0.f, 0.f, 0.f};
        f32x4 ncc = (f32x4){0.f, 0.f, 0.f, 0.f};
        short8 a[4], br[2];                // A: ring-4, lookahead-3
        a[0] = *(const short8*)(aq);
        a[1] = *(const short8*)(aq + 2048);
        a[2] = *(const short8*)(aq + 4096);
        br[0] = *(const short8*)(bb + (boff ^ bsw));
#pragma unroll
        for (int kt = 0; kt < 24; ++kt) {
            const int ca = kt & 3, cb = kt & 1;
            if (kt < 21) a[(kt + 3) & 3] = *(const short8*)(aq + (kt + 3) * 2048);
            if (kt < 23)
                br[cb ^ 1] = *(const short8*)(bb + ((boff + (kt + 1) * 64) ^ bsw));
            acc = __builtin_amdgcn_mfma_f32_16x16x32_bf16(a[ca], br[cb], acc, 0, 0, 0);
            ncc = __builtin_amdgcn_mfma_f32_16x16x32_bf16(br[cb], br[cb], ncc, 0, 0, 0);
        }

        // ---- row norm from Gram diag: C[i][i] at lane ((i>>2)<<4)|i, reg i&3 ----
        float x = ncc[li & 3];
        float dsq = __shfl(x, ((li >> 2) << 4) | li, 64);
        float rk = rsqrtf(dsq);

        // ---- S-tile (C layout: col(n)=li, row(q16)=lg*4+r), scaled ----
#pragma unroll
        for (int r = 0; r < 4; ++r) S[w * 16 + lg * 4 + r][li] = acc[r] * rk;
        asm volatile("s_waitcnt lgkmcnt(0)" ::: "memory");
        __builtin_amdgcn_sched_barrier(0);
        __builtin_amdgcn_s_barrier();
        __builtin_amdgcn_sched_barrier(0);

        // ---- per-tile top-8, all 256 threads (query qd, column quarter jq) ----
        {
            const int nb = tile * TROWS + jq * 4;
#pragma unroll
            for (int j = 0; j < 4; ++j) {
                float v = S[qd][jq * 4 + j]; int n = nb + j;
                INS8(v, n, v8, i8);
            }
        }
        if (nxt >= NTIL) break;
        tile = nxt; cur ^= 1;
    }

    // ---- final 4-way quarter merge (reuse Bb as staging) ----
    __syncthreads();
    float2* mg = (float2*)(&Bb[0][0]);     // 256*8*8B = 16KB <= 24KB
#pragma unroll
    for (int m = 0; m < 8; ++m) mg[t * 8 + m] = make_float2(v8[m], __int_as_float(i8[m]));
    __syncthreads();
    if (t < BQ) {
        float vf[8]; int nf[8];
#pragma unroll
        for (int m = 0; m < 8; ++m) { vf[m] = -FLT_MAX; nf[m] = INT_MAX; }
        for (int s = 0; s < 4; ++s) {
            const float2* rowp = &mg[(t + s * 64) * 8];
#pragma unroll
            for (int m = 0; m < 8; ++m) {
                float v = rowp[m].x; int n = __float_as_int(rowp[m].y);
                INS8(v, n, vf, nf);
            }
        }
        float2* dst = pv + ((size_t)t * NBLKS + blockIdx.x) * 8;
#pragma unroll
        for (int m = 0; m < 8; ++m) dst[m] = make_float2(vf[m], __int_as_float(nf[m]));
    }
}

// ---------- phase 2: merge 512x8 -> top-16 -> exact f32 rescore -> top-5 -> gather ----------
__global__ __launch_bounds__(256) void merge_rescore_kernel(
    const float2* __restrict__ pv,
    const float* __restrict__ q, const float* __restrict__ ke,
    const int* __restrict__ kf, const float* __restrict__ qn,
    float* __restrict__ out) {
    const int qi = blockIdx.x, t = threadIdx.x;
    __shared__ float sv[256][8];
    __shared__ int   si[256][8];
    __shared__ int   ci[T_CAND];
    __shared__ float cs_[T_CAND];
    __shared__ int   fi[K_TOP];

    float v8[8]; int i8[8];
#pragma unroll
    for (int m = 0; m < 8; ++m) { v8[m] = -FLT_MAX; i8[m] = INT_MAX; }

    // coalesced scan of this query's partials [NBLKS*8 = 4096]
    const float2* src = pv + (size_t)qi * NBLKS * 8;
#pragma unroll 4
    for (int c = t; c < NBLKS * 8; c += 256) {
        float2 e = src[c];
        float v = e.x; int n = __float_as_int(e.y);
        INS8(v, n, v8, i8);
    }
#pragma unroll
    for (int m = 0; m < 8; ++m) { sv[t][m] = v8[m]; si[t][m] = i8[m]; }
    __syncthreads();

    // tree merge 256 -> 64 -> 16 -> 4 rows (top-8 each; global rank<=8 survives)
    for (int active = 64; active >= 4; active >>= 2) {
        if (t < active) {
#pragma unroll
            for (int m = 0; m < 8; ++m) { v8[m] = -FLT_MAX; i8[m] = INT_MAX; }
            for (int s = 0; s < 4; ++s) {
                int row = t * 4 + s;
#pragma unroll
                for (int m = 0; m < 8; ++m) {
                    float v = sv[row][m]; int n = si[row][m];
                    INS8(v, n, v8, i8);
                }
            }
        }
        __syncthreads();
        if (t < active) {
#pragma unroll
            for (int m = 0; m < 8; ++m) { sv[t][m] = v8[m]; si[t][m] = i8[m]; }
        }
        __syncthreads();
    }

    // thread 0: 4 rows x 8 -> top-16
    if (t == 0) {
        float v16[T_CAND]; int i16[T_CAND];
#pragma unroll
        for (int m = 0; m < T_CAND; ++m) { v16[m] = -FLT_MAX; i16[m] = INT_MAX; }
        for (int row = 0; row < 4; ++row) {
#pragma unroll
            for (int m = 0; m < 8; ++m) {
                float v = sv[row][m]; int n = si[row][m];
#pragma unroll
                for (int p = 0; p < T_CAND; ++p) {
                    if (v > v16[p]) {
                        float tv = v16[p]; v16[p] = v; v = tv;
                        int ti = i16[p]; i16[p] = n; n = ti;
                    }
                }
            }
        }
#pragma unroll
        for (int m = 0; m < T_CAND; ++m) ci[m] = i16[m];
    }
    __syncthreads();

    // exact f32 rescore; wave w -> candidates w*4..w*4+3
    {
        const int w = t >> 6, lane = t & 63;
        for (int cc = 0; cc < 4; ++cc) {
            int c = w * 4 + cc;
            int row = ci[c];
            const float* kp = ke + (size_t)row * DD + lane * 12;
            const float* qp = q + qi * DD + lane * 12;
            float d = 0.f, ks = 0.f;
#pragma unroll
            for (int i = 0; i < 12; ++i) {
                float kv = kp[i];
                d = fmaf(qp[i], kv, d);
                ks = fmaf(kv, kv, ks);
            }
#pragma unroll
            for (int off = 32; off > 0; off >>= 1) {
                d += __shfl_xor(d, off, 64);
                ks += __shfl_xor(ks, off, 64);
            }
            if (lane == 0)
                cs_[c] = d / fmaxf(qn[qi] * sqrtf(ks), 1e-8f);
        }
    }
    __syncthreads();

    // final top-5 of 16 (tie -> lower index)
    if (t == 0) {
        float v5[K_TOP]; int i5[K_TOP];
#pragma unroll
        for (int m = 0; m < K_TOP; ++m) { v5[m] = -FLT_MAX; i5[m] = INT_MAX; }
        for (int c = 0; c < T_CAND; ++c) {
            float v = cs_[c]; int n = ci[c];
#pragma unroll
            for (int m = 0; m < K_TOP; ++m) {
                bool take = (v > v5[m]) || (v == v5[m] && n < i5[m]);
                if (take) {
                    float tv = v5[m]; v5[m] = v; v = tv;
                    int ti = i5[m]; i5[m] = n; n = ti;
                }
            }
        }
#pragma unroll
        for (int m = 0; m < K_TOP; ++m) fi[m] = i5[m];
    }
    __syncthreads();

    // gather knowledge_full rows (ints < 30000 exact in f32)
    for (int pos = t; pos < K_TOP * LK; pos += 256) {
        int m = pos >> 5, lgi = pos & 31;
        out[(qi * K_TOP + m) * LK + lgi] = (float)kf[(size_t)fi[m] * LK + lgi];
    }
    // gather embed rows
    const int EO = BQ * K_TOP * LK;  // 10240
    for (int m = 0; m < K_TOP; ++m) {
        const float4* srcp = (const float4*)(ke + (size_t)fi[m] * DD);
        float4* dstp = (float4*)(out + EO + (size_t)(qi * K_TOP + m) * DD);
        for (int pos = t; pos < DD / 4; pos += 256) dstp[pos] = srcp[pos];
    }
}

extern "C" void kernel_launch(void* const* d_in, const int* in_sizes, int n_in,
                              void* d_out, int out_size, void* d_ws, size_t ws_size,
                              hipStream_t stream) {
    const float* query = (const float*)d_in[0];
    const float* ke    = (const float*)d_in[1];
    const int*   kf    = (const int*)d_in[2];
    float* out = (float*)d_out;

    // ws layout: pv [64][512][8] float2 (2.1 MB) | qf [24*4*64*8] ushort | qn[64]
    float2* pv = (float2*)d_ws;
    ushort* qf = (ushort*)((char*)d_ws + (size_t)BQ * NBLKS * 8 * sizeof(float2));
    float*  qn = (float*)((char*)qf + (size_t)24 * 4 * 64 * 8 * sizeof(ushort));

    prep_kernel<<<BQ, 256, 0, stream>>>(query, qf, qn);
    sims_kernel<<<NBLKS, 256, 0, stream>>>(qf, ke, pv);
    merge_rescore_kernel<<<BQ, 256, 0, stream>>>(pv, query, ke, kf, qn, out);
}

// Round 12
// 145.538 us; speedup vs baseline: 1.5534x; 1.1254x over previous
//
#include <hip/hip_runtime.h>
#include <cfloat>
#include <climits>

// Retriever: cosine-sim top-5 over 100k knowledge vectors + gather.
// v12 = v11 with the K-loop purged of ALL VMEM: A-fragments preloaded once
// into registers (24 x short8, L2-hot qf), B from single-buffer swizzled LDS.
// Mechanism: vmcnt retires in issue order, so any global load inside the
// K-loop forced a full drain of the next tile's 12-load stage burst
// (priority inversion) -- that was the ~2 TB/s wall of v2..v11.
// Gram-MFMA norms, quarter-parallel top-8 tail, persistent 512 blocks.
// Then merge -> top-16 -> exact f32 rescore -> top-5 -> gather.

#define BQ 64
#define DD 768
#define NK 100000
#define LK 32
#define K_TOP 5
#define TROWS 16                    // ke rows per tile
#define NTIL (NK / TROWS)           // 6250 (exact)
#define NBLKS 512                   // persistent sims blocks (2/CU)
#define T_CAND 16                   // rescore candidate count

typedef __attribute__((ext_vector_type(8))) short short8;
typedef __attribute__((ext_vector_type(4))) float f32x4;

static __device__ __forceinline__ ushort bf16_rtn(float x) {
    uint u = __float_as_uint(x);
    return (ushort)((u + 0x7FFFu + ((u >> 16) & 1u)) >> 16);
}

#define INS8(v, n, va, ia)                                                  \
    _Pragma("unroll")                                                       \
    for (int m_ = 0; m_ < 8; ++m_) {                                        \
        if ((v) > va[m_]) {                                                 \
            float tv_ = va[m_]; va[m_] = (v); (v) = tv_;                    \
            int ti_ = ia[m_]; ia[m_] = (n); (n) = ti_;                      \
        }                                                                   \
    }

// ---------- phase 0: query -> normalized bf16 in FRAGMENT-MAJOR layout ----------
// qf[((kt*4 + (b>>4))*64 + lg*16 + (b&15))*8 + j] = bf16(q[b][kt*32+lg*8+j] * rq)
__global__ __launch_bounds__(256) void prep_kernel(const float* __restrict__ q,
                                                   ushort* __restrict__ qf,
                                                   float* __restrict__ qn) {
    const int b = blockIdx.x, t = threadIdx.x;
    __shared__ float red[4];
    float v[3];
    float s = 0.f;
#pragma unroll
    for (int i = 0; i < 3; ++i) {
        v[i] = q[b * DD + t + i * 256];
        s = fmaf(v[i], v[i], s);
    }
    for (int off = 32; off > 0; off >>= 1) s += __shfl_down(s, off, 64);
    if ((t & 63) == 0) red[t >> 6] = s;
    __syncthreads();
    const float tot = red[0] + red[1] + red[2] + red[3];
    const float rq = rsqrtf(tot);
    const int qb = b >> 4, bi = b & 15;
#pragma unroll
    for (int i = 0; i < 3; ++i) {
        const int k = t + i * 256;
        const int kt = k >> 5, lg = (k >> 3) & 3, j = k & 7;
        qf[((size_t)(kt * 4 + qb) * 64 + lg * 16 + bi) * 8 + j] = bf16_rtn(v[i] * rq);
    }
    if (t == 0) qn[b] = sqrtf(tot);
}

// ---------- phase 1: persistent sims, VMEM-free K-loop, Gram norms ----------
__global__ __launch_bounds__(256) void sims_kernel(const ushort* __restrict__ qf,
                                                   const float* __restrict__ ke,
                                                   float2* __restrict__ pv) {
    __shared__ ushort Bb[TROWS * DD];      // 24576 B single buffer, swizzled
    __shared__ float  S[BQ][17];           // sims tile (bank-spread)

    const int t = threadIdx.x;
    const int w = t >> 6, l = t & 63;
    const int lg = l >> 4, li = l & 15;
    const int qd = t & 63, jq = t >> 6;    // tail: query + column-quarter

    float v8[8]; int i8[8];
#pragma unroll
    for (int m = 0; m < 8; ++m) { v8[m] = -FLT_MAX; i8[m] = INT_MAX; }

    f32x4 sr[4][3];                        // reg-staged 4 rows x 48B/lane
    int tile = blockIdx.x;

    // prologue: issue stage loads for first tile FIRST (oldest in vmcnt queue)
    {
        const float* g = ke + (size_t)(tile * TROWS + w * 4) * DD + l * 4;
#pragma unroll
        for (int i = 0; i < 4; ++i)
#pragma unroll
            for (int c = 0; c < 3; ++c)
                sr[i][c] = *(const f32x4*)(g + i * DD + c * 256);
    }

    // A preload: the wave's 24 fragments, once per kernel (96 VGPR, L2-hot).
    // Issued AFTER the stage loads: waiting on these never drains a stage burst,
    // and nothing in the main loop waits on them again.
    const ushort* aq = qf + (size_t)w * 512 + l * 8;
    short8 A[24];
#pragma unroll
    for (int p = 0; p < 24; ++p) A[p] = *(const short8*)(aq + p * 2048);

    while (true) {
        const int nxt = tile + NBLKS;

        // ---- convert own 4 rows -> raw trunc bf16 -> Bb (swizzled) ----
        char* bb = (char*)Bb;
#pragma unroll
        for (int i = 0; i < 4; ++i) {
            const int row = w * 4 + i;
            const int base = row * 1536 + l * 8;
            const int sw = (row & 7) << 4;
#pragma unroll
            for (int c = 0; c < 3; ++c) {
                uint2 u;
                u.x = __builtin_amdgcn_perm(__float_as_uint(sr[i][c][1]),
                                            __float_as_uint(sr[i][c][0]),
                                            0x07060302u);
                u.y = __builtin_amdgcn_perm(__float_as_uint(sr[i][c][3]),
                                            __float_as_uint(sr[i][c][2]),
                                            0x07060302u);
                *(uint2*)(bb + ((base + c * 512) ^ sw)) = u;
            }
        }
        // ---- issue next tile's stage loads; NOTHING waits vmcnt until the
        //      next convert, so these fly under K-loop + barriers + scan ----
        if (nxt < NTIL) {
            const float* g = ke + (size_t)(nxt * TROWS + w * 4) * DD + l * 4;
#pragma unroll
            for (int i = 0; i < 4; ++i)
#pragma unroll
                for (int c = 0; c < 3; ++c)
                    sr[i][c] = *(const f32x4*)(g + i * DD + c * 256);
        }
        asm volatile("s_waitcnt lgkmcnt(0)" ::: "memory");
        __builtin_amdgcn_sched_barrier(0);
        __builtin_amdgcn_s_barrier();      // raw: does NOT drain vmcnt
        __builtin_amdgcn_sched_barrier(0);

        // ---- K-loop: pure LDS + registers (zero VMEM) ----
        const int boff = li * 1536 + lg * 16;
        const int bsw = (li & 7) << 4;
        f32x4 acc = (f32x4){0.f, 0.f, 0.f, 0.f};
        f32x4 ncc = (f32x4){0.f, 0.f, 0.f, 0.f};
        short8 br[2];
        br[0] = *(const short8*)(bb + (boff ^ bsw));
#pragma unroll
        for (int kt = 0; kt < 24; ++kt) {
            const int cb = kt & 1;
            if (kt < 23)
                br[cb ^ 1] = *(const short8*)(bb + ((boff + (kt + 1) * 64) ^ bsw));
            acc = __builtin_amdgcn_mfma_f32_16x16x32_bf16(A[kt], br[cb], acc, 0, 0, 0);
            ncc = __builtin_amdgcn_mfma_f32_16x16x32_bf16(br[cb], br[cb], ncc, 0, 0, 0);
        }

        // ---- row norm from Gram diag: C[i][i] at lane ((i>>2)<<4)|i, reg i&3 ----
        float x = ncc[li & 3];
        float dsq = __shfl(x, ((li >> 2) << 4) | li, 64);
        float rk = rsqrtf(dsq);

        // ---- S-tile (C layout: col(n)=li, row(q16)=lg*4+r), scaled ----
#pragma unroll
        for (int r = 0; r < 4; ++r) S[w * 16 + lg * 4 + r][li] = acc[r] * rk;
        asm volatile("s_waitcnt lgkmcnt(0)" ::: "memory");
        __builtin_amdgcn_sched_barrier(0);
        __builtin_amdgcn_s_barrier();
        __builtin_amdgcn_sched_barrier(0);

        // ---- per-tile top-8, all 256 threads (query qd, column quarter jq) ----
        {
            const int nb = tile * TROWS + jq * 4;
#pragma unroll
            for (int j = 0; j < 4; ++j) {
                float v = S[qd][jq * 4 + j]; int n = nb + j;
                INS8(v, n, v8, i8);
            }
        }
        if (nxt >= NTIL) break;
        tile = nxt;
    }

    // ---- final 4-way quarter merge (reuse Bb as staging: 16KB <= 24KB) ----
    __syncthreads();
    float2* mg = (float2*)(&Bb[0]);
#pragma unroll
    for (int m = 0; m < 8; ++m) mg[t * 8 + m] = make_float2(v8[m], __int_as_float(i8[m]));
    __syncthreads();
    if (t < BQ) {
        float vf[8]; int nf[8];
#pragma unroll
        for (int m = 0; m < 8; ++m) { vf[m] = -FLT_MAX; nf[m] = INT_MAX; }
        for (int s = 0; s < 4; ++s) {
            const float2* rowp = &mg[(t + s * 64) * 8];
#pragma unroll
            for (int m = 0; m < 8; ++m) {
                float v = rowp[m].x; int n = __float_as_int(rowp[m].y);
                INS8(v, n, vf, nf);
            }
        }
        float2* dst = pv + ((size_t)t * NBLKS + blockIdx.x) * 8;
#pragma unroll
        for (int m = 0; m < 8; ++m) dst[m] = make_float2(vf[m], __int_as_float(nf[m]));
    }
}

// ---------- phase 2: merge 512x8 -> top-16 -> exact f32 rescore -> top-5 -> gather ----------
__global__ __launch_bounds__(256) void merge_rescore_kernel(
    const float2* __restrict__ pv,
    const float* __restrict__ q, const float* __restrict__ ke,
    const int* __restrict__ kf, const float* __restrict__ qn,
    float* __restrict__ out) {
    const int qi = blockIdx.x, t = threadIdx.x;
    __shared__ float sv[256][8];
    __shared__ int   si[256][8];
    __shared__ int   ci[T_CAND];
    __shared__ float cs_[T_CAND];
    __shared__ int   fi[K_TOP];

    float v8[8]; int i8[8];
#pragma unroll
    for (int m = 0; m < 8; ++m) { v8[m] = -FLT_MAX; i8[m] = INT_MAX; }

    // coalesced scan of this query's partials [NBLKS*8 = 4096]
    const float2* src = pv + (size_t)qi * NBLKS * 8;
#pragma unroll 4
    for (int c = t; c < NBLKS * 8; c += 256) {
        float2 e = src[c];
        float v = e.x; int n = __float_as_int(e.y);
        INS8(v, n, v8, i8);
    }
#pragma unroll
    for (int m = 0; m < 8; ++m) { sv[t][m] = v8[m]; si[t][m] = i8[m]; }
    __syncthreads();

    // tree merge 256 -> 64 -> 16 -> 4 rows (top-8 each; global rank<=8 survives)
    for (int active = 64; active >= 4; active >>= 2) {
        if (t < active) {
#pragma unroll
            for (int m = 0; m < 8; ++m) { v8[m] = -FLT_MAX; i8[m] = INT_MAX; }
            for (int s = 0; s < 4; ++s) {
                int row = t * 4 + s;
#pragma unroll
                for (int m = 0; m < 8; ++m) {
                    float v = sv[row][m]; int n = si[row][m];
                    INS8(v, n, v8, i8);
                }
            }
        }
        __syncthreads();
        if (t < active) {
#pragma unroll
            for (int m = 0; m < 8; ++m) { sv[t][m] = v8[m]; si[t][m] = i8[m]; }
        }
        __syncthreads();
    }

    // thread 0: 4 rows x 8 -> top-16
    if (t == 0) {
        float v16[T_CAND]; int i16[T_CAND];
#pragma unroll
        for (int m = 0; m < T_CAND; ++m) { v16[m] = -FLT_MAX; i16[m] = INT_MAX; }
        for (int row = 0; row < 4; ++row) {
#pragma unroll
            for (int m = 0; m < 8; ++m) {
                float v = sv[row][m]; int n = si[row][m];
#pragma unroll
                for (int p = 0; p < T_CAND; ++p) {
                    if (v > v16[p]) {
                        float tv = v16[p]; v16[p] = v; v = tv;
                        int ti = i16[p]; i16[p] = n; n = ti;
                    }
                }
            }
        }
#pragma unroll
        for (int m = 0; m < T_CAND; ++m) ci[m] = i16[m];
    }
    __syncthreads();

    // exact f32 rescore; wave w -> candidates w*4..w*4+3
    {
        const int w = t >> 6, lane = t & 63;
        for (int cc = 0; cc < 4; ++cc) {
            int c = w * 4 + cc;
            int row = ci[c];
            const float* kp = ke + (size_t)row * DD + lane * 12;
            const float* qp = q + qi * DD + lane * 12;
            float d = 0.f, ks = 0.f;
#pragma unroll
            for (int i = 0; i < 12; ++i) {
                float kv = kp[i];
                d = fmaf(qp[i], kv, d);
                ks = fmaf(kv, kv, ks);
            }
#pragma unroll
            for (int off = 32; off > 0; off >>= 1) {
                d += __shfl_xor(d, off, 64);
                ks += __shfl_xor(ks, off, 64);
            }
            if (lane == 0)
                cs_[c] = d / fmaxf(qn[qi] * sqrtf(ks), 1e-8f);
        }
    }
    __syncthreads();

    // final top-5 of 16 (tie -> lower index)
    if (t == 0) {
        float v5[K_TOP]; int i5[K_TOP];
#pragma unroll
        for (int m = 0; m < K_TOP; ++m) { v5[m] = -FLT_MAX; i5[m] = INT_MAX; }
        for (int c = 0; c < T_CAND; ++c) {
            float v = cs_[c]; int n = ci[c];
#pragma unroll
            for (int m = 0; m < K_TOP; ++m) {
                bool take = (v > v5[m]) || (v == v5[m] && n < i5[m]);
                if (take) {
                    float tv = v5[m]; v5[m] = v; v = tv;
                    int ti = i5[m]; i5[m] = n; n = ti;
                }
            }
        }
#pragma unroll
        for (int m = 0; m < K_TOP; ++m) fi[m] = i5[m];
    }
    __syncthreads();

    // gather knowledge_full rows (ints < 30000 exact in f32)
    for (int pos = t; pos < K_TOP * LK; pos += 256) {
        int m = pos >> 5, lgi = pos & 31;
        out[(qi * K_TOP + m) * LK + lgi] = (float)kf[(size_t)fi[m] * LK + lgi];
    }
    // gather embed rows
    const int EO = BQ * K_TOP * LK;  // 10240
    for (int m = 0; m < K_TOP; ++m) {
        const float4* srcp = (const float4*)(ke + (size_t)fi[m] * DD);
        float4* dstp = (float4*)(out + EO + (size_t)(qi * K_TOP + m) * DD);
        for (int pos = t; pos < DD / 4; pos += 256) dstp[pos] = srcp[pos];
    }
}

extern "C" void kernel_launch(void* const* d_in, const int* in_sizes, int n_in,
                              void* d_out, int out_size, void* d_ws, size_t ws_size,
                              hipStream_t stream) {
    const float* query = (const float*)d_in[0];
    const float* ke    = (const float*)d_in[1];
    const int*   kf    = (const int*)d_in[2];
    float* out = (float*)d_out;

    // ws layout: pv [64][512][8] float2 (2.1 MB) | qf [24*4*64*8] ushort | qn[64]
    float2* pv = (float2*)d_ws;
    ushort* qf = (ushort*)((char*)d_ws + (size_t)BQ * NBLKS * 8 * sizeof(float2));
    float*  qn = (float*)((char*)qf + (size_t)24 * 4 * 64 * 8 * sizeof(ushort));

    prep_kernel<<<BQ, 256, 0, stream>>>(query, qf, qn);
    sims_kernel<<<NBLKS, 256, 0, stream>>>(qf, ke, pv);
    merge_rescore_kernel<<<BQ, 256, 0, stream>>>(pv, query, ke, kf, qn, out);
}